// Round 10
// baseline (66.458 us; speedup 1.0000x reference)
//
#include <hip/hip_runtime.h>
#include <stdint.h>

typedef uint32_t u32;
typedef unsigned short u16;

#define LDT 40  // GEMM LDS row stride (elements)

typedef __bf16 bf16x8 __attribute__((ext_vector_type(8)));
typedef float  f32x4  __attribute__((ext_vector_type(4)));
typedef _Float16 h16x2 __attribute__((ext_vector_type(2)));
typedef u32    u32x4  __attribute__((ext_vector_type(4)));

__device__ __forceinline__ float bf2f(u16 x) {
  union { float f; u32 u; } c; c.u = ((u32)x) << 16; return c.f;
}
__device__ __forceinline__ u16 f2bf(float f) {
  union { float f; u32 u; } c; c.f = f;
  u32 b = c.u;
  return (u16)((b + 0x7FFFu + ((b >> 16) & 1u)) >> 16);
}
__device__ __forceinline__ u32 pk2(float lo, float hi) {
  return (u32)f2bf(lo) | ((u32)f2bf(hi) << 16);
}
__device__ __forceinline__ u16 f2h(float f) {
  union { _Float16 h; u16 u; } c; c.h = (_Float16)f; return c.u;
}
__device__ __forceinline__ float h2f(u16 x) {
  union { _Float16 h; u16 u; } c; c.u = x; return (float)c.h;
}
__device__ __forceinline__ u32 h2bf2(u32 w) {  // 2 f16 -> 2 bf16
  return pk2(h2f((u16)(w & 0xFFFF)), h2f((u16)(w >> 16)));
}
__device__ __forceinline__ float fdot2u(u32 a, u32 b, float c) {
  union { u32 u; h16x2 h; } ua, ub; ua.u = a; ub.u = b;
#if __has_builtin(__builtin_amdgcn_fdot2)
  return __builtin_amdgcn_fdot2(ua.h, ub.h, c, false);
#else
  return c + (float)ua.h.x * (float)ub.h.x + (float)ua.h.y * (float)ub.h.y;
#endif
}

// ---------------------------------------------------------------------------
// Kernel 0: z<3: transpose+cast Wq/Wk/Wv (f32 [256][256] -> bf16 WT [n][k]).
//           z==3 (block 0,0): Wg2^T bf16 padded [32][40]  AND  Wg1^T bf16
//           padded [32][256] (rows 24..31 zero).
// ---------------------------------------------------------------------------
__global__ __launch_bounds__(256) void prep_transpose(
    const float* __restrict__ Wq, const float* __restrict__ Wk, const float* __restrict__ Wv,
    const float* __restrict__ Wg2, const float* __restrict__ Wg1,
    u16* __restrict__ WTq, u16* __restrict__ WTk, u16* __restrict__ WTv,
    u16* __restrict__ wg2bf, u16* __restrict__ wg1T)
{
  int z = blockIdx.z, bx = blockIdx.x, by = blockIdx.y;
  int x = threadIdx.x, y = threadIdx.y;  // 32 x 8
  if (z == 3) {
    if (bx || by) return;
    int t = y * 32 + x;
    for (int i = t; i < 1280; i += 256) {
      int j = i / 40, k = i % 40;
      float v = (j < 24 && k < 24) ? Wg2[(size_t)k * 24 + j] : 0.f;
      wg2bf[i] = f2bf(v);
    }
    for (int j = 0; j < 24; j++)
      wg1T[(size_t)j * 256 + t] = f2bf(Wg1[(size_t)t * 24 + j]);
    for (int j = 24; j < 32; j++)
      wg1T[(size_t)j * 256 + t] = 0;
    return;
  }
  __shared__ u16 tile[32][33];
  const float* W  = (z == 0) ? Wq : (z == 1) ? Wk : Wv;
  u16*         WT = (z == 0) ? WTq : (z == 1) ? WTk : WTv;
  for (int yy = y; yy < 32; yy += 8)
    tile[yy][x] = f2bf(W[(size_t)(by * 32 + yy) * 256 + bx * 32 + x]);
  __syncthreads();
  for (int yy = y; yy < 32; yy += 8)
    WT[(size_t)(bx * 32 + yy) * 256 + by * 32 + x] = tile[x][yy];
}

// ---------------------------------------------------------------------------
// Kernel 1: q/k/v projections. BM=64: grid (128 m-tiles, 2 n-blks, 3 mats)
// = 768 blocks (3/CU). Y[8192,256] = X @ W + b (f16 out).
// ---------------------------------------------------------------------------
__global__ __launch_bounds__(256) void gemm_qkv(
    const float* __restrict__ Xq, const float* __restrict__ Xk, const float* __restrict__ Xv,
    const u16* __restrict__ WTq, const u16* __restrict__ WTk, const u16* __restrict__ WTv,
    const float* __restrict__ bq, const float* __restrict__ bk, const float* __restrict__ bv,
    u16* __restrict__ Oq, u16* __restrict__ Ok, u16* __restrict__ Ov)
{
  int z = blockIdx.z;
  const float* X    = (z == 0) ? Xq : (z == 1) ? Xk : Xv;
  const u16*   WT   = (z == 0) ? WTq : (z == 1) ? WTk : WTv;
  const float* bias = (z == 0) ? bq : (z == 1) ? bk : bv;
  u16*         O    = (z == 0) ? Oq : (z == 1) ? Ok : Ov;

  int m0 = blockIdx.x * 64;
  int n0 = blockIdx.y * 128;
  int t = threadIdx.x;
  int lane = t & 63, wid = t >> 6;
  int wr = wid >> 1, wc = wid & 1;
  int fr = lane & 15, fg = lane >> 4;
  int sra = t >> 2;             // 0..63  (A rows)
  int sca = (t & 3) * 8;        // 0,8,16,24
  int srb = t >> 1;             // 0..127 (B rows)
  int scb = (t & 1) * 16;

  __shared__ __align__(16) u16 la[64 * LDT];
  __shared__ __align__(16) u16 lb[128 * LDT];

  f32x4 acc[2][4];
#pragma unroll
  for (int i = 0; i < 2; i++)
#pragma unroll
    for (int j = 0; j < 4; j++) acc[i][j] = (f32x4){0.f, 0.f, 0.f, 0.f};

  for (int kt = 0; kt < 256; kt += 32) {
    const float4* ga = (const float4*)(X + (size_t)(m0 + sra) * 256 + kt + sca);
    float4 a0 = ga[0], a1 = ga[1];
    const uint4* gb = (const uint4*)(WT + (size_t)(n0 + srb) * 256 + kt + scb);
    uint4 b0 = gb[0], b1 = gb[1];

    uint4 wa;
    wa.x = pk2(a0.x, a0.y); wa.y = pk2(a0.z, a0.w);
    wa.z = pk2(a1.x, a1.y); wa.w = pk2(a1.z, a1.w);

    __syncthreads();
    *(uint4*)&la[sra * LDT + sca]     = wa;
    *(uint4*)&lb[srb * LDT + scb]     = b0;
    *(uint4*)&lb[srb * LDT + scb + 8] = b1;
    __syncthreads();

    bf16x8 af[2], bfr[4];
#pragma unroll
    for (int s = 0; s < 2; s++)
      af[s] = *(const bf16x8*)&la[(wr * 32 + s * 16 + fr) * LDT + fg * 8];
#pragma unroll
    for (int j = 0; j < 4; j++)
      bfr[j] = *(const bf16x8*)&lb[(wc * 64 + j * 16 + fr) * LDT + fg * 8];
#pragma unroll
    for (int i = 0; i < 2; i++)
#pragma unroll
      for (int j = 0; j < 4; j++)
        acc[i][j] = __builtin_amdgcn_mfma_f32_16x16x32_bf16(af[i], bfr[j], acc[i][j], 0, 0, 0);
  }

#pragma unroll
  for (int i = 0; i < 2; i++) {
    int rowb = m0 + wr * 32 + i * 16 + fg * 4;
#pragma unroll
    for (int j = 0; j < 4; j++) {
      int col = n0 + wc * 64 + j * 16 + fr;
      float bb = bias[col];
#pragma unroll
      for (int r = 0; r < 4; r++)
        O[(size_t)(rowb + r) * 256 + col] = f2h(acc[i][j][r] + bb);
    }
  }
}

// ---------------------------------------------------------------------------
// Kernel 1b: kg1 = kbuf @ Wg1 (f16 out, stride 32); qadj = qbuf @ Wg1 - bg1.
// ---------------------------------------------------------------------------
__global__ __launch_bounds__(256) void gemm_g1(
    const u16* __restrict__ kbuf, const u16* __restrict__ qbuf,
    const u16* __restrict__ wg1T, const float* __restrict__ bg1,
    u16* __restrict__ kg1, u16* __restrict__ qadj)
{
  int z = blockIdx.y;                      // 0: kg1, 1: qadj
  const u16* X = (z == 0) ? kbuf : qbuf;
  u16*       O = (z == 0) ? kg1 : qadj;

  int m0 = blockIdx.x * 128;
  int t = threadIdx.x;
  int lane = t & 63, wid = t >> 6;
  int fr = lane & 15, fg = lane >> 4;
  int sr = t >> 1;
  int sc = (t & 1) * 16;

  __shared__ __align__(16) u16 la[128 * LDT];
  __shared__ __align__(16) u16 lb[32 * LDT];

  f32x4 acc[2][2];
#pragma unroll
  for (int i = 0; i < 2; i++)
#pragma unroll
    for (int j = 0; j < 2; j++) acc[i][j] = (f32x4){0.f, 0.f, 0.f, 0.f};

  for (int kt = 0; kt < 256; kt += 32) {
    const uint4* ga = (const uint4*)(X + (size_t)(m0 + sr) * 256 + kt + sc);
    uint4 a0 = ga[0], a1 = ga[1];
    uint4 b0, b1;
    if (t < 64) {
      const uint4* gb = (const uint4*)(wg1T + (size_t)sr * 256 + kt + sc);
      b0 = gb[0]; b1 = gb[1];
    }
    uint4 wa0, wa1;
    wa0.x = h2bf2(a0.x); wa0.y = h2bf2(a0.y);
    wa0.z = h2bf2(a0.z); wa0.w = h2bf2(a0.w);
    wa1.x = h2bf2(a1.x); wa1.y = h2bf2(a1.y);
    wa1.z = h2bf2(a1.z); wa1.w = h2bf2(a1.w);

    __syncthreads();
    *(uint4*)&la[sr * LDT + sc]     = wa0;
    *(uint4*)&la[sr * LDT + sc + 8] = wa1;
    if (t < 64) {
      *(uint4*)&lb[sr * LDT + sc]     = b0;
      *(uint4*)&lb[sr * LDT + sc + 8] = b1;
    }
    __syncthreads();

    bf16x8 af[2], bfr[2];
#pragma unroll
    for (int s = 0; s < 2; s++)
      af[s] = *(const bf16x8*)&la[(wid * 32 + s * 16 + fr) * LDT + fg * 8];
#pragma unroll
    for (int s = 0; s < 2; s++)
      bfr[s] = *(const bf16x8*)&lb[(s * 16 + fr) * LDT + fg * 8];
#pragma unroll
    for (int i = 0; i < 2; i++)
#pragma unroll
      for (int j = 0; j < 2; j++)
        acc[i][j] = __builtin_amdgcn_mfma_f32_16x16x32_bf16(af[i], bfr[j], acc[i][j], 0, 0, 0);
  }

#pragma unroll
  for (int i = 0; i < 2; i++) {
    int rowb = m0 + wid * 32 + i * 16 + fg * 4;
#pragma unroll
    for (int j = 0; j < 2; j++) {
      int col = j * 16 + fr;
      if (col < 24) {
        float sub = (z == 1) ? bg1[col] : 0.f;
#pragma unroll
        for (int r = 0; r < 4; r++)
          O[(size_t)(rowb + r) * 32 + col] = f2h(acc[i][j][r] - sub);
      }
    }
  }
}

// ---------------------------------------------------------------------------
// Kernel 2: FUSED edge attention. One 256-thread block per point.
// All gathers/streams issued at kernel start; 3 barriers; softmax denominator
// folded into the PV loop (no separate phase, no att round-trip).
// ---------------------------------------------------------------------------
__global__ __launch_bounds__(256) void attn_fused(
    const u16* __restrict__ qb, const u16* __restrict__ kb, const u16* __restrict__ vb,
    const u16* __restrict__ kg1g, const u16* __restrict__ qadjg,
    const int* __restrict__ ip, const float* __restrict__ raw,
    const float* __restrict__ rpe, const u16* __restrict__ wg2bf,
    const float* __restrict__ bg2g, float* __restrict__ out)
{
  int p = blockIdx.x, t = threadIdx.x;
  int lane = t & 63, w = t >> 6;
  int fr = lane & 15, fg = lane >> 4;
  int n = t >> 3, h = t & 7;

  __shared__ __align__(16) u16   v_s[32 * 264];    // f16 gathered V rows
  __shared__ __align__(16) u16   wg2_s[32 * 40];   // bf16 Wg2^T padded
  __shared__ __align__(16) u16   kg1_s[32 * 40];   // f16 gathered kg1 rows
  __shared__              float qadj_s[24];
  __shared__              float bg2_s[24];
  __shared__              float sh_s[96];
  __shared__              float g_s[32 * 33];
  __shared__              float ev_s[256];         // [n][h] e-values

  int myidx = ip[(size_t)p * 32 + n];

  // ---- early-issue everything ------------------------------------------
  // v rows (gather, -> LDS later)
  int vc0 = (t & 7) * 32;
  const uint4* vp = (const uint4*)(vb + (size_t)myidx * 256 + vc0);
  uint4 v0 = vp[0], v1 = vp[1], v2 = vp[2], v3 = vp[3];
  // kg1 rows (gather)
  uint4 kg1w = {0, 0, 0, 0};
  if ((t & 7) < 4) kg1w = *(const uint4*)(kg1g + (size_t)myidx * 32 + (t & 7) * 8);
  // k row slice (gather, stays in regs)
  const uint4* kr = (const uint4*)(kb + (size_t)myidx * 256 + h * 32);
  uint4 k0 = kr[0], k1 = kr[1], k2 = kr[2], k3 = kr[3];
  // streams (non-temporal)
  const u32x4* qr = (const u32x4*)(qb + (size_t)p * 256 + h * 32);
  u32x4 q0 = __builtin_nontemporal_load(qr + 0);
  u32x4 q1 = __builtin_nontemporal_load(qr + 1);
  u32x4 q2 = __builtin_nontemporal_load(qr + 2);
  u32x4 q3 = __builtin_nontemporal_load(qr + 3);
  float rw = __builtin_nontemporal_load(raw + (size_t)p * 256 + t);
  uint4 wgw = {0, 0, 0, 0};
  if (t < 160) wgw = ((const uint4*)wg2bf)[t];
  float rx = 0.f, ry = 0.f, rz = 0.f;
  if (t >= 160 && t < 192) {
    int nn = t - 160;
    rx = __builtin_nontemporal_load(rpe + (size_t)p * 96 + nn * 3 + 0);
    ry = __builtin_nontemporal_load(rpe + (size_t)p * 96 + nn * 3 + 1);
    rz = __builtin_nontemporal_load(rpe + (size_t)p * 96 + nn * 3 + 2);
  }
  u16 qaw = 0;
  if (t >= 192 && t < 216)
    qaw = __builtin_nontemporal_load(qadjg + (size_t)p * 32 + (t - 192));
  float bgw = 0.f;
  if (t >= 224 && t < 248) bgw = bg2g[t - 224];

  // ---- Phase A: LDS staging --------------------------------------------
  if ((t & 7) < 4) *(uint4*)&kg1_s[n * 40 + (t & 7) * 8] = kg1w;
  if (t < 160) *(uint4*)&wg2_s[t * 8] = wgw;
  else if (t < 192) {
    int nn = t - 160;
    float rl = sqrtf(rx * rx + ry * ry + rz * rz);
    float inv = 1.f / fmaxf(rl, 1e-12f);
    float tt2 = fminf(fmaxf((rl - 0.001f) * 250.f, 0.f), 1.f);
    float cut = 0.5f * (1.f - cosf(tt2 * 3.14159265358979f));
    float s3c = 1.7320508075688772f * inv * cut;
    sh_s[nn * 3 + 0] = rx * s3c; sh_s[nn * 3 + 1] = ry * s3c; sh_s[nn * 3 + 2] = rz * s3c;
  }
  else if (t >= 192 && t < 216) qadj_s[t - 192] = h2f(qaw);
  else if (t >= 224 && t < 248) bg2_s[t - 224] = bgw;
  {
    u16* d = &v_s[n * 264 + vc0];
    ((uint4*)d)[0] = v0; *(uint4*)(d + 8) = v1;
    *(uint4*)(d + 16) = v2; *(uint4*)(d + 24) = v3;
  }
  __syncthreads();

  // ---- Phase B: MLP g = relu(kg1_g - qadj) @ Wg2 + bg2 (1 MFMA per wave)
  {
    int mt = w & 1, jt = w >> 1;
    union { u32 u[4]; bf16x8 v; } a;
    if (fg < 3) {
      const u16*   krow = &kg1_s[(mt * 16 + fr) * 40 + fg * 8];
      const float* qrow = &qadj_s[fg * 8];
      float x0 = fmaxf(h2f(krow[0]) - qrow[0], 0.f), x1 = fmaxf(h2f(krow[1]) - qrow[1], 0.f);
      float x2 = fmaxf(h2f(krow[2]) - qrow[2], 0.f), x3 = fmaxf(h2f(krow[3]) - qrow[3], 0.f);
      float x4 = fmaxf(h2f(krow[4]) - qrow[4], 0.f), x5 = fmaxf(h2f(krow[5]) - qrow[5], 0.f);
      float x6 = fmaxf(h2f(krow[6]) - qrow[6], 0.f), x7 = fmaxf(h2f(krow[7]) - qrow[7], 0.f);
      a.u[0] = pk2(x0, x1); a.u[1] = pk2(x2, x3);
      a.u[2] = pk2(x4, x5); a.u[3] = pk2(x6, x7);
    } else {
      a.u[0] = a.u[1] = a.u[2] = a.u[3] = 0;
    }
    bf16x8 b = *(const bf16x8*)&wg2_s[(jt * 16 + fr) * 40 + fg * 8];
    f32x4 g = (f32x4){0.f, 0.f, 0.f, 0.f};
    g = __builtin_amdgcn_mfma_f32_16x16x32_bf16(a.v, b, g, 0, 0, 0);
    int j = jt * 16 + fr;
    float bb = (j < 24) ? bg2_s[j] : 0.f;
    int e0 = mt * 16 + fg * 4;
#pragma unroll
    for (int r = 0; r < 4; r++)
      g_s[(e0 + r) * 33 + j] = g[r] + bb;
  }
  __syncthreads();

  // ---- Phase C: dot from REGISTERS + pos + raw -> e-values --------------
  {
    float dot = 0.f;
    dot = fdot2u(k0.x, q0[0], dot); dot = fdot2u(k0.y, q0[1], dot);
    dot = fdot2u(k0.z, q0[2], dot); dot = fdot2u(k0.w, q0[3], dot);
    dot = fdot2u(k1.x, q1[0], dot); dot = fdot2u(k1.y, q1[1], dot);
    dot = fdot2u(k1.z, q1[2], dot); dot = fdot2u(k1.w, q1[3], dot);
    dot = fdot2u(k2.x, q2[0], dot); dot = fdot2u(k2.y, q2[1], dot);
    dot = fdot2u(k2.z, q2[2], dot); dot = fdot2u(k2.w, q2[3], dot);
    dot = fdot2u(k3.x, q3[0], dot); dot = fdot2u(k3.y, q3[1], dot);
    dot = fdot2u(k3.z, q3[2], dot); dot = fdot2u(k3.w, q3[3], dot);
    float pos = g_s[n * 33 + h * 3 + 0] * sh_s[n * 3 + 0]
              + g_s[n * 33 + h * 3 + 1] * sh_s[n * 3 + 1]
              + g_s[n * 33 + h * 3 + 2] * sh_s[n * 3 + 2];
    ev_s[t] = __expf((dot + pos + rw) * 0.17677669529663687f);
  }
  __syncthreads();

  // ---- Phase D: PV + inline denominator. Thread t = output column. ------
  {
    int hh = t >> 5;
    float s = 0.f, acc = 0.f;
#pragma unroll
    for (int nn = 0; nn < 32; nn++) {
      float evn = ev_s[nn * 8 + hh];
      s += evn;
      acc += evn * h2f(v_s[nn * 264 + t]);
    }
    __builtin_nontemporal_store(acc / s, out + (size_t)p * 256 + t);
  }
}

// ---------------------------------------------------------------------------
extern "C" void kernel_launch(void* const* d_in, const int* in_sizes, int n_in,
                              void* d_out, int out_size, void* d_ws, size_t ws_size,
                              hipStream_t stream) {
  const float* query = (const float*)d_in[0];
  const float* key_x = (const float*)d_in[1];
  const float* value = (const float*)d_in[2];
  const int*   index_pair = (const int*)d_in[3];
  const float* raw  = (const float*)d_in[4];
  const float* rpe  = (const float*)d_in[5];
  const float* Wq = (const float*)d_in[6];
  const float* bq = (const float*)d_in[7];
  const float* Wk = (const float*)d_in[8];
  const float* bk = (const float*)d_in[9];
  const float* Wv = (const float*)d_in[10];
  const float* bv = (const float*)d_in[11];
  const float* Wg1 = (const float*)d_in[12];
  const float* bg1 = (const float*)d_in[13];
  const float* Wg2 = (const float*)d_in[14];
  const float* bg2 = (const float*)d_in[15];
  float* out = (float*)d_out;

  char* ws = (char*)d_ws;
  u16*   qbuf  = (u16*)(ws);                           // 4MB  [8192][256] f16
  u16*   kbuf  = (u16*)(ws + (4u << 20));              // 4MB
  u16*   vbuf  = (u16*)(ws + (8u << 20));              // 4MB
  u16*   qadj  = (u16*)(ws + (12u << 20));             // 512KB [8192][32] f16
  u16*   kg1   = (u16*)(ws + (12u << 20) + 524288);    // 512KB
  u16*   WTq   = (u16*)(ws + (13u << 20));             // 128KB each
  u16*   WTk   = WTq + 65536;
  u16*   WTv   = WTk + 65536;
  u16*   wg2bf = WTv + 65536;                          // [32][40] bf16
  u16*   wg1T  = wg2bf + 1280;                         // [32][256] bf16

  prep_transpose<<<dim3(8, 8, 4), dim3(32, 8, 1), 0, stream>>>(
      Wq, Wk, Wv, Wg2, Wg1, WTq, WTk, WTv, wg2bf, wg1T);
  gemm_qkv<<<dim3(128, 2, 3), 256, 0, stream>>>(
      query, key_x, value, WTq, WTk, WTv, bq, bk, bv, qbuf, kbuf, vbuf);
  gemm_g1<<<dim3(64, 2), 256, 0, stream>>>(
      kbuf, qbuf, wg1T, bg1, kg1, qadj);
  attn_fused<<<8192, 256, 0, stream>>>(
      qbuf, kbuf, vbuf, kg1, qadj, index_pair, raw, rpe, wg2bf, bg2, out);
}

// Round 11
// 63.872 us; speedup vs baseline: 1.0405x; 1.0405x over previous
//
#include <hip/hip_runtime.h>
#include <stdint.h>

typedef uint32_t u32;
typedef unsigned short u16;

#define LDT 40  // GEMM LDS row stride (elements)

typedef __bf16 bf16x8 __attribute__((ext_vector_type(8)));
typedef float  f32x4  __attribute__((ext_vector_type(4)));
typedef _Float16 h16x2 __attribute__((ext_vector_type(2)));
typedef u32    u32x4  __attribute__((ext_vector_type(4)));
typedef u32    u32x2  __attribute__((ext_vector_type(2)));
typedef float  f32x4v __attribute__((ext_vector_type(4)));

__device__ __forceinline__ float bf2f(u16 x) {
  union { float f; u32 u; } c; c.u = ((u32)x) << 16; return c.f;
}
__device__ __forceinline__ u16 f2bf(float f) {
  union { float f; u32 u; } c; c.f = f;
  u32 b = c.u;
  return (u16)((b + 0x7FFFu + ((b >> 16) & 1u)) >> 16);
}
__device__ __forceinline__ u32 pk2(float lo, float hi) {
  return (u32)f2bf(lo) | ((u32)f2bf(hi) << 16);
}
__device__ __forceinline__ u16 f2h(float f) {
  union { _Float16 h; u16 u; } c; c.h = (_Float16)f; return c.u;
}
__device__ __forceinline__ float h2f(u16 x) {
  union { _Float16 h; u16 u; } c; c.u = x; return (float)c.h;
}
__device__ __forceinline__ u32 h2bf2(u32 w) {  // 2 f16 -> 2 bf16
  return pk2(h2f((u16)(w & 0xFFFF)), h2f((u16)(w >> 16)));
}
__device__ __forceinline__ float fdot2u(u32 a, u32 b, float c) {
  union { u32 u; h16x2 h; } ua, ub; ua.u = a; ub.u = b;
#if __has_builtin(__builtin_amdgcn_fdot2)
  return __builtin_amdgcn_fdot2(ua.h, ub.h, c, false);
#else
  return c + (float)ua.h.x * (float)ub.h.x + (float)ua.h.y * (float)ub.h.y;
#endif
}

// ---------------------------------------------------------------------------
// Kernel 0: z<3: transpose+cast Wq/Wk/Wv (f32 [256][256] -> bf16 WT [n][k]).
//           z==3 (block 0,0): Wg2^T bf16 padded [32][40]  AND  Wg1^T bf16
//           padded [32][256] (rows 24..31 zero).
// ---------------------------------------------------------------------------
__global__ __launch_bounds__(256) void prep_transpose(
    const float* __restrict__ Wq, const float* __restrict__ Wk, const float* __restrict__ Wv,
    const float* __restrict__ Wg2, const float* __restrict__ Wg1,
    u16* __restrict__ WTq, u16* __restrict__ WTk, u16* __restrict__ WTv,
    u16* __restrict__ wg2bf, u16* __restrict__ wg1T)
{
  int z = blockIdx.z, bx = blockIdx.x, by = blockIdx.y;
  int x = threadIdx.x, y = threadIdx.y;  // 32 x 8
  if (z == 3) {
    if (bx || by) return;
    int t = y * 32 + x;
    for (int i = t; i < 1280; i += 256) {
      int j = i / 40, k = i % 40;
      float v = (j < 24 && k < 24) ? Wg2[(size_t)k * 24 + j] : 0.f;
      wg2bf[i] = f2bf(v);
    }
    for (int j = 0; j < 24; j++)
      wg1T[(size_t)j * 256 + t] = f2bf(Wg1[(size_t)t * 24 + j]);
    for (int j = 24; j < 32; j++)
      wg1T[(size_t)j * 256 + t] = 0;
    return;
  }
  __shared__ u16 tile[32][33];
  const float* W  = (z == 0) ? Wq : (z == 1) ? Wk : Wv;
  u16*         WT = (z == 0) ? WTq : (z == 1) ? WTk : WTv;
  for (int yy = y; yy < 32; yy += 8)
    tile[yy][x] = f2bf(W[(size_t)(by * 32 + yy) * 256 + bx * 32 + x]);
  __syncthreads();
  for (int yy = y; yy < 32; yy += 8)
    WT[(size_t)(bx * 32 + yy) * 256 + by * 32 + x] = tile[x][yy];
}

// ---------------------------------------------------------------------------
// Kernel 1: q/k/v projections. BM=64: grid (128 m-tiles, 2 n-blks, 3 mats)
// = 768 blocks (3/CU). Y[8192,256] = X @ W + b (f16 out).
// ---------------------------------------------------------------------------
__global__ __launch_bounds__(256) void gemm_qkv(
    const float* __restrict__ Xq, const float* __restrict__ Xk, const float* __restrict__ Xv,
    const u16* __restrict__ WTq, const u16* __restrict__ WTk, const u16* __restrict__ WTv,
    const float* __restrict__ bq, const float* __restrict__ bk, const float* __restrict__ bv,
    u16* __restrict__ Oq, u16* __restrict__ Ok, u16* __restrict__ Ov)
{
  int z = blockIdx.z;
  const float* X    = (z == 0) ? Xq : (z == 1) ? Xk : Xv;
  const u16*   WT   = (z == 0) ? WTq : (z == 1) ? WTk : WTv;
  const float* bias = (z == 0) ? bq : (z == 1) ? bk : bv;
  u16*         O    = (z == 0) ? Oq : (z == 1) ? Ok : Ov;

  int m0 = blockIdx.x * 64;
  int n0 = blockIdx.y * 128;
  int t = threadIdx.x;
  int lane = t & 63, wid = t >> 6;
  int wr = wid >> 1, wc = wid & 1;
  int fr = lane & 15, fg = lane >> 4;
  int sra = t >> 2;             // 0..63  (A rows)
  int sca = (t & 3) * 8;        // 0,8,16,24
  int srb = t >> 1;             // 0..127 (B rows)
  int scb = (t & 1) * 16;

  __shared__ __align__(16) u16 la[64 * LDT];
  __shared__ __align__(16) u16 lb[128 * LDT];

  f32x4 acc[2][4];
#pragma unroll
  for (int i = 0; i < 2; i++)
#pragma unroll
    for (int j = 0; j < 4; j++) acc[i][j] = (f32x4){0.f, 0.f, 0.f, 0.f};

  for (int kt = 0; kt < 256; kt += 32) {
    const float4* ga = (const float4*)(X + (size_t)(m0 + sra) * 256 + kt + sca);
    float4 a0 = ga[0], a1 = ga[1];
    const uint4* gb = (const uint4*)(WT + (size_t)(n0 + srb) * 256 + kt + scb);
    uint4 b0 = gb[0], b1 = gb[1];

    uint4 wa;
    wa.x = pk2(a0.x, a0.y); wa.y = pk2(a0.z, a0.w);
    wa.z = pk2(a1.x, a1.y); wa.w = pk2(a1.z, a1.w);

    __syncthreads();
    *(uint4*)&la[sra * LDT + sca]     = wa;
    *(uint4*)&lb[srb * LDT + scb]     = b0;
    *(uint4*)&lb[srb * LDT + scb + 8] = b1;
    __syncthreads();

    bf16x8 af[2], bfr[4];
#pragma unroll
    for (int s = 0; s < 2; s++)
      af[s] = *(const bf16x8*)&la[(wr * 32 + s * 16 + fr) * LDT + fg * 8];
#pragma unroll
    for (int j = 0; j < 4; j++)
      bfr[j] = *(const bf16x8*)&lb[(wc * 64 + j * 16 + fr) * LDT + fg * 8];
#pragma unroll
    for (int i = 0; i < 2; i++)
#pragma unroll
      for (int j = 0; j < 4; j++)
        acc[i][j] = __builtin_amdgcn_mfma_f32_16x16x32_bf16(af[i], bfr[j], acc[i][j], 0, 0, 0);
  }

#pragma unroll
  for (int i = 0; i < 2; i++) {
    int rowb = m0 + wr * 32 + i * 16 + fg * 4;
#pragma unroll
    for (int j = 0; j < 4; j++) {
      int col = n0 + wc * 64 + j * 16 + fr;
      float bb = bias[col];
#pragma unroll
      for (int r = 0; r < 4; r++)
        O[(size_t)(rowb + r) * 256 + col] = f2h(acc[i][j][r] + bb);
    }
  }
}

// ---------------------------------------------------------------------------
// Kernel 1b: kg1 = kbuf @ Wg1 (f16 out, stride 32); qadj = qbuf @ Wg1 - bg1.
// BM=64: grid (128, 2) = 256 blocks (1/CU) — halves the tail vs BM=128.
// ---------------------------------------------------------------------------
__global__ __launch_bounds__(256) void gemm_g1(
    const u16* __restrict__ kbuf, const u16* __restrict__ qbuf,
    const u16* __restrict__ wg1T, const float* __restrict__ bg1,
    u16* __restrict__ kg1, u16* __restrict__ qadj)
{
  int z = blockIdx.y;                      // 0: kg1, 1: qadj
  const u16* X = (z == 0) ? kbuf : qbuf;
  u16*       O = (z == 0) ? kg1 : qadj;

  int m0 = blockIdx.x * 64;
  int t = threadIdx.x;
  int lane = t & 63, wid = t >> 6;
  int fr = lane & 15, fg = lane >> 4;
  int sra = t >> 2;             // 0..63 (A rows)
  int sca = (t & 3) * 8;        // 8-elem chunks
  int srb = t >> 1;             // B (only t<64): 0..31
  int scb = (t & 1) * 16;

  __shared__ __align__(16) u16 la[64 * LDT];
  __shared__ __align__(16) u16 lb[32 * LDT];

  f32x4 acc[2];
  acc[0] = (f32x4){0.f, 0.f, 0.f, 0.f};
  acc[1] = (f32x4){0.f, 0.f, 0.f, 0.f};

  for (int kt = 0; kt < 256; kt += 32) {
    const uint4* ga = (const uint4*)(X + (size_t)(m0 + sra) * 256 + kt + sca);
    uint4 a0 = ga[0];                        // 8 f16
    uint4 b0, b1;
    if (t < 64) {
      const uint4* gb = (const uint4*)(wg1T + (size_t)srb * 256 + kt + scb);
      b0 = gb[0]; b1 = gb[1];
    }
    uint4 wa;
    wa.x = h2bf2(a0.x); wa.y = h2bf2(a0.y);
    wa.z = h2bf2(a0.z); wa.w = h2bf2(a0.w);

    __syncthreads();
    *(uint4*)&la[sra * LDT + sca] = wa;
    if (t < 64) {
      *(uint4*)&lb[srb * LDT + scb]     = b0;
      *(uint4*)&lb[srb * LDT + scb + 8] = b1;
    }
    __syncthreads();

    bf16x8 af = *(const bf16x8*)&la[(wid * 16 + fr) * LDT + fg * 8];
    bf16x8 bf0 = *(const bf16x8*)&lb[(fr) * LDT + fg * 8];
    bf16x8 bf1 = *(const bf16x8*)&lb[(16 + fr) * LDT + fg * 8];
    acc[0] = __builtin_amdgcn_mfma_f32_16x16x32_bf16(af, bf0, acc[0], 0, 0, 0);
    acc[1] = __builtin_amdgcn_mfma_f32_16x16x32_bf16(af, bf1, acc[1], 0, 0, 0);
  }

  int rowb = m0 + wid * 16 + fg * 4;
#pragma unroll
  for (int j = 0; j < 2; j++) {
    int col = j * 16 + fr;
    if (col < 24) {
      float sub = (z == 1) ? bg1[col] : 0.f;
#pragma unroll
      for (int r = 0; r < 4; r++)
        O[(size_t)(rowb + r) * 32 + col] = f2h(acc[j][r] - sub);
    }
  }
}

// ---------------------------------------------------------------------------
// Kernel 2: logits + softmax -> att f16 [P][32 n][8 h], normalized.
// All gathers/streams prefetched at kernel start; 3 barriers; denominator
// computed per-thread (broadcast LDS reads, no wave-0 phase).
// ---------------------------------------------------------------------------
__global__ __launch_bounds__(256) void attn_logits(
    const u16* __restrict__ qb, const u16* __restrict__ kb,
    const u16* __restrict__ kg1g, const u16* __restrict__ qadjg,
    const int* __restrict__ ip, const float* __restrict__ raw,
    const float* __restrict__ rpe, const u16* __restrict__ wg2bf,
    const float* __restrict__ bg2g, u16* __restrict__ attg)
{
  int p = blockIdx.x, t = threadIdx.x;
  int lane = t & 63, w = t >> 6;
  int fr = lane & 15, fg = lane >> 4;
  int n = t >> 3, h = t & 7;

  __shared__ __align__(16) u16   wg2_s[32 * 40];   // bf16 Wg2^T padded
  __shared__ __align__(16) u16   kg1_s[32 * 40];   // f16 gathered kg1 rows
  __shared__              float qadj_s[24];
  __shared__              float bg2_s[24];
  __shared__              float sh_s[96];
  __shared__              float g_s[32 * 33];
  __shared__              float ev_s[256];

  int myidx = ip[(size_t)p * 32 + n];

  // ---- early-issue LDS-destined loads
  uint4 kg1w = {0, 0, 0, 0};
  if ((t & 7) < 4) kg1w = *(const uint4*)(kg1g + (size_t)myidx * 32 + (t & 7) * 8);
  uint4 wgw = {0, 0, 0, 0};
  if (t < 160) wgw = ((const uint4*)wg2bf)[t];
  float rx = 0.f, ry = 0.f, rz = 0.f;
  if (t >= 160 && t < 192) {
    int nn = t - 160;
    rx = __builtin_nontemporal_load(rpe + (size_t)p * 96 + nn * 3 + 0);
    ry = __builtin_nontemporal_load(rpe + (size_t)p * 96 + nn * 3 + 1);
    rz = __builtin_nontemporal_load(rpe + (size_t)p * 96 + nn * 3 + 2);
  }
  u16 qaw = 0;
  if (t >= 192 && t < 216)
    qaw = __builtin_nontemporal_load(qadjg + (size_t)p * 32 + (t - 192));
  float bgw = 0.f;
  if (t >= 224 && t < 248) bgw = bg2g[t - 224];

  // ---- prefetch: gathered k row (64B) + streamed q row slice + raw, -> regs
  const uint4* kr = (const uint4*)(kb + (size_t)myidx * 256 + h * 32);
  uint4 k0 = kr[0], k1 = kr[1], k2 = kr[2], k3 = kr[3];
  const u32x4* qr = (const u32x4*)(qb + (size_t)p * 256 + h * 32);
  u32x4 q0 = __builtin_nontemporal_load(qr + 0);
  u32x4 q1 = __builtin_nontemporal_load(qr + 1);
  u32x4 q2 = __builtin_nontemporal_load(qr + 2);
  u32x4 q3 = __builtin_nontemporal_load(qr + 3);
  float rw = __builtin_nontemporal_load(raw + (size_t)p * 256 + t);

  // ---- Phase A: LDS stores + sh
  if ((t & 7) < 4) *(uint4*)&kg1_s[n * 40 + (t & 7) * 8] = kg1w;
  if (t < 160) *(uint4*)&wg2_s[t * 8] = wgw;
  else if (t < 192) {
    int nn = t - 160;
    float rl = sqrtf(rx * rx + ry * ry + rz * rz);
    float inv = 1.f / fmaxf(rl, 1e-12f);
    float tt2 = fminf(fmaxf((rl - 0.001f) * 250.f, 0.f), 1.f);
    float cut = 0.5f * (1.f - cosf(tt2 * 3.14159265358979f));
    float s3c = 1.7320508075688772f * inv * cut;
    sh_s[nn * 3 + 0] = rx * s3c; sh_s[nn * 3 + 1] = ry * s3c; sh_s[nn * 3 + 2] = rz * s3c;
  }
  else if (t >= 192 && t < 216) qadj_s[t - 192] = h2f(qaw);
  else if (t >= 224 && t < 248) bg2_s[t - 224] = bgw;
  __syncthreads();

  // ---- Phase B: MLP g = relu(kg1_g - qadj) @ Wg2 + bg2 (1 MFMA per wave)
  {
    int mt = w & 1, jt = w >> 1;
    union { u32 u[4]; bf16x8 v; } a;
    if (fg < 3) {
      const u16*   krow = &kg1_s[(mt * 16 + fr) * 40 + fg * 8];
      const float* qrow = &qadj_s[fg * 8];
      float x0 = fmaxf(h2f(krow[0]) - qrow[0], 0.f), x1 = fmaxf(h2f(krow[1]) - qrow[1], 0.f);
      float x2 = fmaxf(h2f(krow[2]) - qrow[2], 0.f), x3 = fmaxf(h2f(krow[3]) - qrow[3], 0.f);
      float x4 = fmaxf(h2f(krow[4]) - qrow[4], 0.f), x5 = fmaxf(h2f(krow[5]) - qrow[5], 0.f);
      float x6 = fmaxf(h2f(krow[6]) - qrow[6], 0.f), x7 = fmaxf(h2f(krow[7]) - qrow[7], 0.f);
      a.u[0] = pk2(x0, x1); a.u[1] = pk2(x2, x3);
      a.u[2] = pk2(x4, x5); a.u[3] = pk2(x6, x7);
    } else {
      a.u[0] = a.u[1] = a.u[2] = a.u[3] = 0;
    }
    bf16x8 b = *(const bf16x8*)&wg2_s[(jt * 16 + fr) * 40 + fg * 8];
    f32x4 g = (f32x4){0.f, 0.f, 0.f, 0.f};
    g = __builtin_amdgcn_mfma_f32_16x16x32_bf16(a.v, b, g, 0, 0, 0);
    int j = jt * 16 + fr;
    float bb = (j < 24) ? bg2_s[j] : 0.f;
    int e0 = mt * 16 + fg * 4;
#pragma unroll
    for (int r = 0; r < 4; r++)
      g_s[(e0 + r) * 33 + j] = g[r] + bb;
  }
  __syncthreads();

  // ---- Phase C: dot from REGISTERS + pos + raw -> e-values
  float ev;
  {
    float dot = 0.f;
    dot = fdot2u(k0.x, q0[0], dot); dot = fdot2u(k0.y, q0[1], dot);
    dot = fdot2u(k0.z, q0[2], dot); dot = fdot2u(k0.w, q0[3], dot);
    dot = fdot2u(k1.x, q1[0], dot); dot = fdot2u(k1.y, q1[1], dot);
    dot = fdot2u(k1.z, q1[2], dot); dot = fdot2u(k1.w, q1[3], dot);
    dot = fdot2u(k2.x, q2[0], dot); dot = fdot2u(k2.y, q2[1], dot);
    dot = fdot2u(k2.z, q2[2], dot); dot = fdot2u(k2.w, q2[3], dot);
    dot = fdot2u(k3.x, q3[0], dot); dot = fdot2u(k3.y, q3[1], dot);
    dot = fdot2u(k3.z, q3[2], dot); dot = fdot2u(k3.w, q3[3], dot);
    float pos = g_s[n * 33 + h * 3 + 0] * sh_s[n * 3 + 0]
              + g_s[n * 33 + h * 3 + 1] * sh_s[n * 3 + 1]
              + g_s[n * 33 + h * 3 + 2] * sh_s[n * 3 + 2];
    ev = __expf((dot + pos + rw) * 0.17677669529663687f);
    ev_s[t] = ev;
  }
  __syncthreads();

  // ---- Phase D: per-thread denominator (broadcast LDS reads) + store
  {
    float s = 0.f;
#pragma unroll
    for (int nn = 0; nn < 32; nn++) s += ev_s[nn * 8 + h];
    __builtin_nontemporal_store(f2h(ev / s), attg + (size_t)p * 256 + t);
  }
}

// ---------------------------------------------------------------------------
// Kernel 3: PV. 4 points/block, 1 wave/point (wave-private, no barrier).
// Gathers ONLY vbuf (4MB). att read + out write non-temporal.
// ---------------------------------------------------------------------------
__global__ __launch_bounds__(256) void attn_pv(
    const u16* __restrict__ vb, const u16* __restrict__ attg,
    const int* __restrict__ ip, float* __restrict__ out)
{
  int t = threadIdx.x, wid = t >> 6, l = t & 63;
  int p = blockIdx.x * 4 + wid;
  __shared__ __align__(8) u16 att_s[4][256];
  __shared__ int idx_s[4][32];

  u32x2 aw = __builtin_nontemporal_load((const u32x2*)(attg + (size_t)p * 256 + l * 4));
  *(u32x2*)&att_s[wid][l * 4] = aw;
  if (l < 32) idx_s[wid][l] = ip[(size_t)p * 32 + l];

  int hh = l >> 3;
  float a0 = 0.f, a1 = 0.f, a2 = 0.f, a3 = 0.f;
#pragma unroll
  for (int n = 0; n < 32; n++) {
    float wt = h2f(att_s[wid][n * 8 + hh]);
    uint2 vv = *(const uint2*)(vb + (size_t)idx_s[wid][n] * 256 + l * 4);
    a0 += wt * h2f((u16)(vv.x & 0xFFFF));
    a1 += wt * h2f((u16)(vv.x >> 16));
    a2 += wt * h2f((u16)(vv.y & 0xFFFF));
    a3 += wt * h2f((u16)(vv.y >> 16));
  }
  f32x4v r; r[0] = a0; r[1] = a1; r[2] = a2; r[3] = a3;
  __builtin_nontemporal_store(r, (f32x4v*)(out + (size_t)p * 256 + l * 4));
}

// ---------------------------------------------------------------------------
extern "C" void kernel_launch(void* const* d_in, const int* in_sizes, int n_in,
                              void* d_out, int out_size, void* d_ws, size_t ws_size,
                              hipStream_t stream) {
  const float* query = (const float*)d_in[0];
  const float* key_x = (const float*)d_in[1];
  const float* value = (const float*)d_in[2];
  const int*   index_pair = (const int*)d_in[3];
  const float* raw  = (const float*)d_in[4];
  const float* rpe  = (const float*)d_in[5];
  const float* Wq = (const float*)d_in[6];
  const float* bq = (const float*)d_in[7];
  const float* Wk = (const float*)d_in[8];
  const float* bk = (const float*)d_in[9];
  const float* Wv = (const float*)d_in[10];
  const float* bv = (const float*)d_in[11];
  const float* Wg1 = (const float*)d_in[12];
  const float* bg1 = (const float*)d_in[13];
  const float* Wg2 = (const float*)d_in[14];
  const float* bg2 = (const float*)d_in[15];
  float* out = (float*)d_out;

  char* ws = (char*)d_ws;
  u16*   qbuf  = (u16*)(ws);                           // 4MB  [8192][256] f16
  u16*   kbuf  = (u16*)(ws + (4u << 20));              // 4MB
  u16*   vbuf  = (u16*)(ws + (8u << 20));              // 4MB
  u16*   attb  = (u16*)(ws + (12u << 20));             // 4MB  [8192][32][8] f16
  u16*   qadj  = (u16*)(ws + (16u << 20));             // 512KB [8192][32] f16
  u16*   kg1   = (u16*)(ws + (16u << 20) + 524288);    // 512KB
  u16*   WTq   = (u16*)(ws + (17u << 20));             // 128KB each
  u16*   WTk   = WTq + 65536;
  u16*   WTv   = WTk + 65536;
  u16*   wg2bf = WTv + 65536;                          // [32][40] bf16
  u16*   wg1T  = wg2bf + 1280;                         // [32][256] bf16

  prep_transpose<<<dim3(8, 8, 4), dim3(32, 8, 1), 0, stream>>>(
      Wq, Wk, Wv, Wg2, Wg1, WTq, WTk, WTv, wg2bf, wg1T);
  gemm_qkv<<<dim3(128, 2, 3), 256, 0, stream>>>(
      query, key_x, value, WTq, WTk, WTv, bq, bk, bv, qbuf, kbuf, vbuf);
  gemm_g1<<<dim3(128, 2), 256, 0, stream>>>(
      kbuf, qbuf, wg1T, bg1, kg1, qadj);
  attn_logits<<<8192, 256, 0, stream>>>(
      qbuf, kbuf, kg1, qadj, index_pair, raw, rpe, wg2bf, bg2, attb);
  attn_pv<<<2048, 256, 0, stream>>>(
      vbuf, attb, index_pair, out);
}